// Round 4
// baseline (198.992 us; speedup 1.0000x reference)
//
#include <hip/hip_runtime.h>

// TrajLoss: sum over i of (x[i]-pred[i])^2 + (y[i]-pred[i+1])^2
// N = 16,777,216; pred has N+1 elements. Memory-bound streaming reduction.
//
// R2/R3: the R0/R1 strided scalar load pred[base+4] (64 lanes x 16B stride =
// 16 line requests per 256 useful bytes) is replaced by an UNALIGNED float4
// load at pred+4i+1 (dwordx4 needs only 4B alignment on gfx950). All four
// streams are now contiguous dwordx4. x/y loads are non-temporal (no reuse).
// R3 build fix: use clang ext_vector_type instead of HIP_vector_type for
// __builtin_nontemporal_load.

typedef float fx4 __attribute__((ext_vector_type(4)));

__global__ void TrajLoss_zero_kernel(float* out) {
    if (threadIdx.x == 0 && blockIdx.x == 0) out[0] = 0.0f;
}

__global__ __launch_bounds__(256) void TrajLoss_6141803233879_kernel(
    const float* __restrict__ pred,
    const float* __restrict__ x,
    const float* __restrict__ y,
    float* __restrict__ out,
    int n4,   // n / 4 (float4 count)
    int n)    // total elements
{
    const int tid    = blockIdx.x * blockDim.x + threadIdx.x;
    const int stride = gridDim.x * blockDim.x;

    float a0 = 0.0f, a1 = 0.0f, a2 = 0.0f, a3 = 0.0f;
    const fx4* x4 = (const fx4*)x;
    const fx4* y4 = (const fx4*)y;
    const fx4* p4 = (const fx4*)pred;

    #pragma unroll 4
    for (int i = tid; i < n4; i += stride) {
        fx4 xv = __builtin_nontemporal_load(x4 + i);
        fx4 yv = __builtin_nontemporal_load(y4 + i);
        fx4 pa = p4[i];                                        // pred[4i .. 4i+3]
        fx4 pb = *(const fx4*)(pred + (i << 2) + 1);           // pred[4i+1 .. 4i+4], 4B-aligned
        float dx, dy;
        dx = xv.x - pa.x; dy = yv.x - pb.x; a0 += dx*dx + dy*dy;
        dx = xv.y - pa.y; dy = yv.y - pb.y; a1 += dx*dx + dy*dy;
        dx = xv.z - pa.z; dy = yv.z - pb.z; a2 += dx*dx + dy*dy;
        dx = xv.w - pa.w; dy = yv.w - pb.w; a3 += dx*dx + dy*dy;
    }

    float acc = (a0 + a1) + (a2 + a3);

    // Scalar tail (n not divisible by 4) — dead code for N=16.7M.
    if (tid == 0) {
        for (int j = n4 << 2; j < n; ++j) {
            float dx = x[j] - pred[j];
            float dy = y[j] - pred[j + 1];
            acc += dx * dx + dy * dy;
        }
    }

    // Wave-64 reduce
    #pragma unroll
    for (int off = 32; off > 0; off >>= 1)
        acc += __shfl_down(acc, off, 64);

    __shared__ float smem[4];   // 256 threads = 4 waves
    const int lane = threadIdx.x & 63;
    const int wave = threadIdx.x >> 6;
    if (lane == 0) smem[wave] = acc;
    __syncthreads();

    if (threadIdx.x == 0) {
        float s = smem[0] + smem[1] + smem[2] + smem[3];
        atomicAdd(out, s);   // device-scope by default on gfx950
    }
}

extern "C" void kernel_launch(void* const* d_in, const int* in_sizes, int n_in,
                              void* d_out, int out_size, void* d_ws, size_t ws_size,
                              hipStream_t stream) {
    const float* pred = (const float*)d_in[0];   // N+1 floats
    const float* x    = (const float*)d_in[1];   // N floats
    const float* y    = (const float*)d_in[2];   // N floats
    float* out = (float*)d_out;

    const int n  = in_sizes[1];
    const int n4 = n >> 2;

    TrajLoss_zero_kernel<<<1, 64, 0, stream>>>(out);

    const int block = 256;
    const int grid = 4096;   // 1,048,576 threads -> 4 float4 iters/thread at N=16.7M
    TrajLoss_6141803233879_kernel<<<grid, block, 0, stream>>>(pred, x, y, out, n4, n);
}